// Round 11
// baseline (398.638 us; speedup 1.0000x reference)
//
#include <hip/hip_runtime.h>
#include <cstddef>

#define N_NODES  100000
#define N_EDGES  600000
#define N_GRAPHS 64

__device__ __forceinline__ void atomAddF(float* p, float v) {
    // gfx950 has HW global fp32 atomic add; unsafeAtomicAdd guarantees the HW path.
    unsafeAtomicAdd(p, v);
}

// compile-time float4 element select (folds to member access when i is literal)
__device__ __forceinline__ float f4get(const float4& v, int i) {
    return i == 0 ? v.x : i == 1 ? v.y : i == 2 ? v.z : v.w;
}

// global -> LDS direct DMA, 16B per lane. Dest must be wave-uniform base;
// HW writes lane l at base + l*16. Global src address is per-lane.
typedef __attribute__((address_space(1))) void GV;
typedef __attribute__((address_space(3))) void LV;
__device__ __forceinline__ void gload16(const float* g, float* l) {
    __builtin_amdgcn_global_load_lds((GV*)g, (LV*)l, 16, 0, 0);
}

// ---------------------------------------------------------------------------
// deg[n] = in-degree (int)
__global__ __launch_bounds__(256) void deg_count(const int* __restrict__ dst,
                                                 int* __restrict__ deg) {
    int e = blockIdx.x * 256 + threadIdx.x;
    if (e < N_EDGES) atomicAdd(deg + dst[e], 1);
}

// ---------------------------------------------------------------------------
// alloc_ranges: parallel CSR range allocation (order of node ranges arbitrary;
// only per-node contiguity matters for an unordered sum).
__global__ __launch_bounds__(256)
void alloc_ranges(const int* __restrict__ deg, int* __restrict__ beg,
                  int* __restrict__ cur, int* __restrict__ counter) {
    int n = blockIdx.x * 256 + threadIdx.x;
    int d = (n < N_NODES) ? deg[n] : 0;
    int lane = threadIdx.x & 63, wid = threadIdx.x >> 6;
    int incl = d;
#pragma unroll
    for (int o = 1; o < 64; o <<= 1) {
        int v = __shfl_up(incl, o);
        if (lane >= o) incl += v;
    }
    __shared__ int wsum[4];
    __shared__ int blockBase;
    if (lane == 63) wsum[wid] = incl;
    __syncthreads();
    if (threadIdx.x == 0) {
        int tot = wsum[0] + wsum[1] + wsum[2] + wsum[3];
        blockBase = atomicAdd(counter, tot);
    }
    __syncthreads();
    int base = blockBase;
    for (int w = 0; w < wid; ++w) base += wsum[w];
    int start = base + incl - d;
    if (n < N_NODES) { beg[n] = start; cur[n] = start; }
}

// ---------------------------------------------------------------------------
// CSR fill: csr_src[cur[d]++] = src[e].  Afterwards cur[n] = END offset.
__global__ __launch_bounds__(256)
void csr_fill(const int* __restrict__ src, const int* __restrict__ dst,
              int* __restrict__ cur, int* __restrict__ csr_src) {
    int e = blockIdx.x * 256 + threadIdx.x;
    if (e >= N_EDGES) return;
    int p = atomicAdd(cur + dst[e], 1);
    csr_src[p] = src[e];
}

// ---------------------------------------------------------------------------
// helper for gemm1's B tile (idx in [0,800): k=idx/50, col chunk=idx%50)
__device__ __forceinline__ float4 loadB1(const float* __restrict__ Ws,
                                         const float* __restrict__ Wn,
                                         int idx, int k0) {
    int k = idx / 50, n = (idx % 50) * 4;
    int gk = k0 + k;
    return (n < 100) ? *reinterpret_cast<const float4*>(Ws + gk * 100 + n)
                     : *reinterpret_cast<const float4*>(Wn + gk * 100 + (n - 100));
}

// ---------------------------------------------------------------------------
// GEMM1: [S1|N1][100000 x 200] = feat[100000 x 128] @ [Wself1 | Wneigh1]
// BM=40, BN=200 (feat read once), KB=16, DOUBLE-BUFFERED: per kt, next A-tile
// gload_lds + next B-tile global->reg loads are issued BEFORE the current
// compute (~1000cy FMA hides ~500-900cy latency); B regs ds_write after
// compute; ONE barrier per kt.  LDS 2x15.4=30.7KB -> 5 blocks/CU;
// launch_bounds(256,5) -> 102-VGPR cap, need ~90 -> no spill.
// A source pre-swizzle (u&3)^((r>>2)&3), read chunk g^(tr&3): conflict-free.
// B-read ~4-way conflict inherent (25 float4 addrs over 8 bank-slots).
__global__ __launch_bounds__(256, 5)
void gemm1(const float* __restrict__ feat, const float* __restrict__ Wself,
           const float* __restrict__ Wneigh,
           float* __restrict__ S1, float* __restrict__ N1) {
    __shared__ float As[2][40 * 16];
    __shared__ float Bs[2][16][200];
    const int tid  = threadIdx.x;
    const int m0   = blockIdx.x * 40;
    const int wave = tid >> 6;
    const int lane = tid & 63;
    const bool active = tid < 250;
    const int tr  = tid / 25;        // 0..9 (rows tr*4 .. tr*4+3)
    const int tcc = tid % 25;        // cols tcc*4..+3 of S1 AND of N1
    const int sw  = tr & 3;
    // B-store coordinates for the 4 strided chunks
    const int bk0 = tid / 50,          bn0 = (tid % 50) * 4;
    const int bk1 = (tid + 256) / 50,  bn1 = ((tid + 256) % 50) * 4;
    const int bk2 = (tid + 512) / 50,  bn2 = ((tid + 512) % 50) * 4;
    const int bk3 = (tid + 768) / 50,  bn3 = ((tid + 768) % 50) * 4;

    float4 acc0[4], acc1[4];
#pragma unroll
    for (int i = 0; i < 4; ++i) {
        acc0[i] = make_float4(0.f, 0.f, 0.f, 0.f);
        acc1[i] = make_float4(0.f, 0.f, 0.f, 0.f);
    }

    // ---- prologue: stage kt=0 into buffer 0
    if (lane < 40) {
        int u  = wave * 40 + lane;
        int r  = u >> 2;
        int k4 = (u & 3) ^ ((r >> 2) & 3);
        gload16(feat + (size_t)(m0 + r) * 128 + k4 * 4, &As[0][wave * 160]);
    }
    {
        float4 v0 = loadB1(Wself, Wneigh, tid,       0);
        float4 v1 = loadB1(Wself, Wneigh, tid + 256, 0);
        float4 v2 = loadB1(Wself, Wneigh, tid + 512, 0);
        *reinterpret_cast<float4*>(&Bs[0][bk0][bn0]) = v0;
        *reinterpret_cast<float4*>(&Bs[0][bk1][bn1]) = v1;
        *reinterpret_cast<float4*>(&Bs[0][bk2][bn2]) = v2;
        if (tid < 32) {
            float4 v3 = loadB1(Wself, Wneigh, tid + 768, 0);
            *reinterpret_cast<float4*>(&Bs[0][bk3][bn3]) = v3;
        }
    }
    __syncthreads();

    for (int kt = 0; kt < 8; ++kt) {
        const int cb = kt & 1, nb = cb ^ 1;
        const bool pf = (kt < 7);
        float4 bv0, bv1, bv2, bv3;
        if (pf) {
            const int k0n = (kt + 1) * 16;
            // next A tile -> LDS (async DMA; drained by end-of-iter barrier)
            if (lane < 40) {
                int u  = wave * 40 + lane;
                int r  = u >> 2;
                int k4 = (u & 3) ^ ((r >> 2) & 3);
                gload16(feat + (size_t)(m0 + r) * 128 + k0n + k4 * 4, &As[nb][wave * 160]);
            }
            // next B tile -> registers (use lands after compute, at the ds_write)
            bv0 = loadB1(Wself, Wneigh, tid,       k0n);
            bv1 = loadB1(Wself, Wneigh, tid + 256, k0n);
            bv2 = loadB1(Wself, Wneigh, tid + 512, k0n);
            if (tid < 32) bv3 = loadB1(Wself, Wneigh, tid + 768, k0n);
        }

        if (active) {
            const int abase = tr * 64;             // (tr*4 rows) * 16 floats
#pragma unroll
            for (int g = 0; g < 4; ++g) {
                const int ac = ((g ^ sw) << 2);    // swizzled chunk offset
                const float4 a0 = *reinterpret_cast<const float4*>(&As[cb][abase +  0 + ac]);
                const float4 a1 = *reinterpret_cast<const float4*>(&As[cb][abase + 16 + ac]);
                const float4 a2 = *reinterpret_cast<const float4*>(&As[cb][abase + 32 + ac]);
                const float4 a3 = *reinterpret_cast<const float4*>(&As[cb][abase + 48 + ac]);
#pragma unroll
                for (int kl = 0; kl < 4; ++kl) {
                    const int k = g * 4 + kl;
                    const float4 b0 = *reinterpret_cast<const float4*>(&Bs[cb][k][tcc * 4]);
                    const float4 b1 = *reinterpret_cast<const float4*>(&Bs[cb][k][100 + tcc * 4]);
                    const float v0 = f4get(a0, kl), v1 = f4get(a1, kl);
                    const float v2 = f4get(a2, kl), v3 = f4get(a3, kl);
                    acc0[0].x = fmaf(v0, b0.x, acc0[0].x); acc0[0].y = fmaf(v0, b0.y, acc0[0].y);
                    acc0[0].z = fmaf(v0, b0.z, acc0[0].z); acc0[0].w = fmaf(v0, b0.w, acc0[0].w);
                    acc1[0].x = fmaf(v0, b1.x, acc1[0].x); acc1[0].y = fmaf(v0, b1.y, acc1[0].y);
                    acc1[0].z = fmaf(v0, b1.z, acc1[0].z); acc1[0].w = fmaf(v0, b1.w, acc1[0].w);
                    acc0[1].x = fmaf(v1, b0.x, acc0[1].x); acc0[1].y = fmaf(v1, b0.y, acc0[1].y);
                    acc0[1].z = fmaf(v1, b0.z, acc0[1].z); acc0[1].w = fmaf(v1, b0.w, acc0[1].w);
                    acc1[1].x = fmaf(v1, b1.x, acc1[1].x); acc1[1].y = fmaf(v1, b1.y, acc1[1].y);
                    acc1[1].z = fmaf(v1, b1.z, acc1[1].z); acc1[1].w = fmaf(v1, b1.w, acc1[1].w);
                    acc0[2].x = fmaf(v2, b0.x, acc0[2].x); acc0[2].y = fmaf(v2, b0.y, acc0[2].y);
                    acc0[2].z = fmaf(v2, b0.z, acc0[2].z); acc0[2].w = fmaf(v2, b0.w, acc0[2].w);
                    acc1[2].x = fmaf(v2, b1.x, acc1[2].x); acc1[2].y = fmaf(v2, b1.y, acc1[2].y);
                    acc1[2].z = fmaf(v2, b1.z, acc1[2].z); acc1[2].w = fmaf(v2, b1.w, acc1[2].w);
                    acc0[3].x = fmaf(v3, b0.x, acc0[3].x); acc0[3].y = fmaf(v3, b0.y, acc0[3].y);
                    acc0[3].z = fmaf(v3, b0.z, acc0[3].z); acc0[3].w = fmaf(v3, b0.w, acc0[3].w);
                    acc1[3].x = fmaf(v3, b1.x, acc1[3].x); acc1[3].y = fmaf(v3, b1.y, acc1[3].y);
                    acc1[3].z = fmaf(v3, b1.z, acc1[3].z); acc1[3].w = fmaf(v3, b1.w, acc1[3].w);
                }
            }
        }

        if (pf) {   // ds_write B regs into next buffer (vmcnt wait lands here)
            *reinterpret_cast<float4*>(&Bs[nb][bk0][bn0]) = bv0;
            *reinterpret_cast<float4*>(&Bs[nb][bk1][bn1]) = bv1;
            *reinterpret_cast<float4*>(&Bs[nb][bk2][bn2]) = bv2;
            if (tid < 32)
                *reinterpret_cast<float4*>(&Bs[nb][bk3][bn3]) = bv3;
        }
        __syncthreads();   // compute done + A gloads drained + B writes visible
    }

    if (active) {
        const int c = tcc * 4;
#pragma unroll
        for (int i = 0; i < 4; ++i) {
            int gr = m0 + tr * 4 + i;              // always < N_NODES (grid exact)
            *reinterpret_cast<float4*>(S1 + (size_t)gr * 100 + c) = acc0[i];
            *reinterpret_cast<float4*>(N1 + (size_t)gr * 100 + c) = acc1[i];
        }
    }
}

// ---------------------------------------------------------------------------
// aggregate1 + fused h1 epilogue: h1[n] = relu(S1[n] + (sum N1[src])*inv + b1).
// 8 nodes/256-block, 32 lanes/node (25 live), float4 per lane, 4x-unrolled
// gather (more loads in flight on the latency-bound L2/L3 gather).
__global__ __launch_bounds__(256)
void aggregate1(const float* __restrict__ N1, const float* __restrict__ S1,
                const float* __restrict__ b1, const int* __restrict__ csr_src,
                const int* __restrict__ beg, const int* __restrict__ cur,
                float* __restrict__ h1) {
    int n  = blockIdx.x * 8 + (threadIdx.x >> 5);
    int c4 = threadIdx.x & 31;
    if (n >= N_NODES || c4 >= 25) return;
    int b = beg[n], end = cur[n];
    float4 acc = make_float4(0.f, 0.f, 0.f, 0.f);
    int j = b;
    for (; j + 3 < end; j += 4) {
        int s0 = csr_src[j], s1 = csr_src[j + 1], s2 = csr_src[j + 2], s3 = csr_src[j + 3];
        float4 v0 = *reinterpret_cast<const float4*>(N1 + (size_t)s0 * 100 + c4 * 4);
        float4 v1 = *reinterpret_cast<const float4*>(N1 + (size_t)s1 * 100 + c4 * 4);
        float4 v2 = *reinterpret_cast<const float4*>(N1 + (size_t)s2 * 100 + c4 * 4);
        float4 v3 = *reinterpret_cast<const float4*>(N1 + (size_t)s3 * 100 + c4 * 4);
        acc.x += v0.x + v1.x; acc.y += v0.y + v1.y;
        acc.z += v0.z + v1.z; acc.w += v0.w + v1.w;
        acc.x += v2.x + v3.x; acc.y += v2.y + v3.y;
        acc.z += v2.z + v3.z; acc.w += v2.w + v3.w;
    }
    for (; j + 1 < end; j += 2) {
        int s0 = csr_src[j], s1 = csr_src[j + 1];
        float4 v0 = *reinterpret_cast<const float4*>(N1 + (size_t)s0 * 100 + c4 * 4);
        float4 v1 = *reinterpret_cast<const float4*>(N1 + (size_t)s1 * 100 + c4 * 4);
        acc.x += v0.x + v1.x; acc.y += v0.y + v1.y;
        acc.z += v0.z + v1.z; acc.w += v0.w + v1.w;
    }
    if (j < end) {
        int s = csr_src[j];
        float4 v = *reinterpret_cast<const float4*>(N1 + (size_t)s * 100 + c4 * 4);
        acc.x += v.x; acc.y += v.y; acc.z += v.z; acc.w += v.w;
    }
    float inv = 1.0f / (float)max(end - b, 1);
    float4 s  = *reinterpret_cast<const float4*>(S1 + (size_t)n * 100 + c4 * 4);
    float4 bb = *reinterpret_cast<const float4*>(b1 + c4 * 4);
    float4 h;
    h.x = fmaxf(fmaf(acc.x, inv, s.x) + bb.x, 0.f);
    h.y = fmaxf(fmaf(acc.y, inv, s.y) + bb.y, 0.f);
    h.z = fmaxf(fmaf(acc.z, inv, s.z) + bb.z, 0.f);
    h.w = fmaxf(fmaf(acc.w, inv, s.w) + bb.w, 0.f);
    *reinterpret_cast<float4*>(h1 + (size_t)n * 100 + c4 * 4) = h;
}

// ---------------------------------------------------------------------------
// GEMM2: C[100000 x 40] = h1 @ [Wself2 | Wneigh2].  BM=64, K=100 (single
// tile).  A-tile pure copy of h1 -> global_load_lds.  B = live 40 cols.
__global__ __launch_bounds__(256)
void gemm2(const float* __restrict__ h1,
           const float* __restrict__ Ws2, const float* __restrict__ Wn2,
           float* __restrict__ S2, float* __restrict__ N2) {
    __shared__ float As[64 * 100];  // [r][k] linear, 25.6KB
    __shared__ float Bs[100][40];   // 16KB
    const int tid  = threadIdx.x;
    const int m0   = blockIdx.x * 64;
    const int wave = tid >> 6;
    const int lane = tid & 63;

    // A tile: 1600 16B-units via gload (linear dest)
#pragma unroll
    for (int t = 0; t < 7; ++t) {
        int u0 = t * 256 + wave * 64;
        if (u0 < 1600) {
            int u  = u0 + lane;
            int r  = u / 25, c4 = u % 25;
            int gr = m0 + r; if (gr >= N_NODES) gr = N_NODES - 1;  // tail clamp
            gload16(h1 + (size_t)gr * 100 + c4 * 4, &As[u0 * 4]);
        }
    }
    // B tile: 100 k x 10 float4
    for (int idx = tid; idx < 1000; idx += 256) {
        int k = idx / 10, n4 = idx % 10;
        int n = n4 * 4;
        float4 v;
        if (n < 20) v = *reinterpret_cast<const float4*>(Ws2 + k * 20 + n);
        else        v = *reinterpret_cast<const float4*>(Wn2 + k * 20 + (n - 20));
        *reinterpret_cast<float4*>(&Bs[k][n]) = v;
    }
    __syncthreads();

    const int tr = tid >> 4, tc = tid & 15;
    if (tc < 10) {
        float acc[4][4] = {};
#pragma unroll 4
        for (int k = 0; k < 100; ++k) {
            float a0 = As[(tr * 4 + 0) * 100 + k];
            float a1 = As[(tr * 4 + 1) * 100 + k];
            float a2 = As[(tr * 4 + 2) * 100 + k];
            float a3 = As[(tr * 4 + 3) * 100 + k];
            float4 b = *reinterpret_cast<const float4*>(&Bs[k][tc * 4]);
            acc[0][0] += a0 * b.x; acc[0][1] += a0 * b.y; acc[0][2] += a0 * b.z; acc[0][3] += a0 * b.w;
            acc[1][0] += a1 * b.x; acc[1][1] += a1 * b.y; acc[1][2] += a1 * b.z; acc[1][3] += a1 * b.w;
            acc[2][0] += a2 * b.x; acc[2][1] += a2 * b.y; acc[2][2] += a2 * b.z; acc[2][3] += a2 * b.w;
            acc[3][0] += a3 * b.x; acc[3][1] += a3 * b.y; acc[3][2] += a3 * b.z; acc[3][3] += a3 * b.w;
        }
#pragma unroll
        for (int i = 0; i < 4; ++i) {
            int gr = m0 + tr * 4 + i;
            if (gr >= N_NODES) continue;
            int n = tc * 4;
            float4 v = make_float4(acc[i][0], acc[i][1], acc[i][2], acc[i][3]);
            if (n < 20) *reinterpret_cast<float4*>(S2 + (size_t)gr * 20 + n) = v;
            else        *reinterpret_cast<float4*>(N2 + (size_t)gr * 20 + (n - 20)) = v;
        }
    }
}

// ---------------------------------------------------------------------------
// aggregate2 + fused h2 epilogue: h2 = relu(S2 + (sum N2[src])*inv + b2).
// 32 nodes per 256-block, 8 lanes/node (5 live), 4x-unrolled.  Zero atomics.
__global__ __launch_bounds__(256)
void aggregate2(const float* __restrict__ N2, const float* __restrict__ S2,
                const float* __restrict__ b2, const int* __restrict__ csr_src,
                const int* __restrict__ beg, const int* __restrict__ cur,
                float* __restrict__ h2) {
    int n  = blockIdx.x * 32 + (threadIdx.x >> 3);
    int c4 = threadIdx.x & 7;
    if (n >= N_NODES || c4 >= 5) return;
    int b = beg[n], end = cur[n];
    float4 acc = make_float4(0.f, 0.f, 0.f, 0.f);
    int j = b;
    for (; j + 3 < end; j += 4) {
        int s0 = csr_src[j], s1 = csr_src[j + 1], s2 = csr_src[j + 2], s3 = csr_src[j + 3];
        float4 v0 = *reinterpret_cast<const float4*>(N2 + (size_t)s0 * 20 + c4 * 4);
        float4 v1 = *reinterpret_cast<const float4*>(N2 + (size_t)s1 * 20 + c4 * 4);
        float4 v2 = *reinterpret_cast<const float4*>(N2 + (size_t)s2 * 20 + c4 * 4);
        float4 v3 = *reinterpret_cast<const float4*>(N2 + (size_t)s3 * 20 + c4 * 4);
        acc.x += v0.x + v1.x; acc.y += v0.y + v1.y;
        acc.z += v0.z + v1.z; acc.w += v0.w + v1.w;
        acc.x += v2.x + v3.x; acc.y += v2.y + v3.y;
        acc.z += v2.z + v3.z; acc.w += v2.w + v3.w;
    }
    for (; j + 1 < end; j += 2) {
        int s0 = csr_src[j], s1 = csr_src[j + 1];
        float4 v0 = *reinterpret_cast<const float4*>(N2 + (size_t)s0 * 20 + c4 * 4);
        float4 v1 = *reinterpret_cast<const float4*>(N2 + (size_t)s1 * 20 + c4 * 4);
        acc.x += v0.x + v1.x; acc.y += v0.y + v1.y;
        acc.z += v0.z + v1.z; acc.w += v0.w + v1.w;
    }
    if (j < end) {
        int s = csr_src[j];
        float4 v = *reinterpret_cast<const float4*>(N2 + (size_t)s * 20 + c4 * 4);
        acc.x += v.x; acc.y += v.y; acc.z += v.z; acc.w += v.w;
    }
    float inv = 1.0f / (float)max(end - b, 1);
    float4 s  = *reinterpret_cast<const float4*>(S2 + (size_t)n * 20 + c4 * 4);
    float4 bb = *reinterpret_cast<const float4*>(b2 + c4 * 4);
    float4 h;
    h.x = fmaxf(fmaf(acc.x, inv, s.x) + bb.x, 0.f);
    h.y = fmaxf(fmaf(acc.y, inv, s.y) + bb.y, 0.f);
    h.z = fmaxf(fmaf(acc.z, inv, s.z) + bb.z, 0.f);
    h.w = fmaxf(fmaf(acc.w, inv, s.w) + bb.w, 0.f);
    *reinterpret_cast<float4*>(h2 + (size_t)n * 20 + c4 * 4) = h;
}

// ---------------------------------------------------------------------------
// pool: per-graph sums + counts of h2.  graph_ids sorted -> most waves
// uniform -> wave shfl-reduce, 20 atomics/wave.
__global__ __launch_bounds__(256)
void pool_kernel(const float* __restrict__ h2, const int* __restrict__ gids,
                 float* __restrict__ pool, float* __restrict__ cnt) {
    int n = blockIdx.x * 256 + threadIdx.x;
    float h[20];
    int g = -1;
    if (n < N_NODES) {
        g = gids[n];
#pragma unroll
        for (int q = 0; q < 5; ++q) {
            float4 v = *reinterpret_cast<const float4*>(h2 + (size_t)n * 20 + q * 4);
            h[q * 4 + 0] = v.x; h[q * 4 + 1] = v.y;
            h[q * 4 + 2] = v.z; h[q * 4 + 3] = v.w;
        }
    } else {
#pragma unroll
        for (int c = 0; c < 20; ++c) h[c] = 0.f;
    }
    unsigned long long act = __ballot(n < N_NODES);
    int gfirst = __shfl(g, 0);
    bool uniform = __all(g == gfirst);
    if (uniform) {
        if (gfirst >= 0) {
#pragma unroll
            for (int c = 0; c < 20; ++c)
                for (int off2 = 32; off2 > 0; off2 >>= 1)
                    h[c] += __shfl_down(h[c], off2);
            if ((threadIdx.x & 63) == 0) {
                for (int c = 0; c < 20; ++c) atomAddF(&pool[gfirst * 20 + c], h[c]);
                atomAddF(&cnt[gfirst], (float)__popcll(act));
            }
        }
    } else if (n < N_NODES) {
        for (int c = 0; c < 20; ++c) atomAddF(&pool[g * 20 + c], h[c]);
        atomAddF(&cnt[g], 1.0f);
    }
}

// ---------------------------------------------------------------------------
// head: hg = pool/cnt; out = relu(hg@fc1+b1)@fc2+b2.  One block, thread per graph.
__global__ __launch_bounds__(64)
void head(const float* __restrict__ pool, const float* __restrict__ cnt,
          const float* __restrict__ fc1w, const float* __restrict__ fc1b,
          const float* __restrict__ fc2w, const float* __restrict__ fc2b,
          float* __restrict__ out) {
    int g = threadIdx.x;
    if (g >= N_GRAPHS) return;
    float inv = 1.0f / fmaxf(cnt[g], 1.0f);
    float hg[20];
    for (int c = 0; c < 20; ++c) hg[c] = pool[g * 20 + c] * inv;
    float o = fc2b[0];
    for (int j = 0; j < 10; ++j) {
        float t = fc1b[j];
        for (int c = 0; c < 20; ++c) t = fmaf(hg[c], fc1w[c * 10 + j], t);
        o = fmaf(fmaxf(t, 0.f), fc2w[j], o);
    }
    out[g] = o;
}

// ---------------------------------------------------------------------------
extern "C" void kernel_launch(void* const* d_in, const int* in_sizes, int n_in,
                              void* d_out, int out_size, void* d_ws, size_t ws_size,
                              hipStream_t stream) {
    const float* feat   = (const float*)d_in[0];
    const float* Wself1 = (const float*)d_in[1];
    const float* Wneigh1= (const float*)d_in[2];
    const float* b1     = (const float*)d_in[3];
    const float* Wself2 = (const float*)d_in[4];
    const float* Wneigh2= (const float*)d_in[5];
    const float* b2     = (const float*)d_in[6];
    const float* fc1w   = (const float*)d_in[7];
    const float* fc1b   = (const float*)d_in[8];
    const float* fc2w   = (const float*)d_in[9];
    const float* fc2b   = (const float*)d_in[10];
    const int*   src    = (const int*)d_in[11];
    const int*   dst    = (const int*)d_in[12];
    const int*   gids   = (const int*)d_in[13];
    float* ws = (float*)d_ws;

    // workspace layout (floats); regions recycled across phases
    float* S1 = ws;                        // 10,000,000 (dead after aggregate1)
    float* N1 = ws + 10000000;             // 10,000,000 (dead after aggregate1)
    float* h1 = ws + 20000000;             // 10,000,000
    float* S2 = N1;                        //  2,000,000
    float* N2 = N1 + 2000000;              //  2,000,000
    float* h2 = S1;                        //  2,000,000
    int*   deg  = (int*)(ws + 30000000);   //    100,000
    float* pool = ws + 30100000;           //      1,280
    float* cnt  = ws + 30101280;           //         64
    int*   ctr  = (int*)(ws + 30101344);   //          1 (range-alloc counter)
    int*   beg  = (int*)(ws + 30101360);   //    100,000 (CSR range starts)
    int*   cur  = (int*)(ws + 30201360);   //    100,000 (fill cursors -> range ends)
    int*   csr  = (int*)(ws + 30301360);   //    600,000 (CSR src indices)
    // total: 30,901,360 floats = ~117.9 MiB

    // zero deg + pool + cnt + ctr in one shot (contiguous region)
    hipMemsetAsync(deg, 0, (100000 + 1280 + 64 + 16) * sizeof(float), stream);

    deg_count<<<(N_EDGES + 255) / 256, 256, 0, stream>>>(dst, deg);
    alloc_ranges<<<(N_NODES + 255) / 256, 256, 0, stream>>>(deg, beg, cur, ctr);
    csr_fill<<<(N_EDGES + 255) / 256, 256, 0, stream>>>(src, dst, cur, csr);

    gemm1<<<N_NODES / 40, 256, 0, stream>>>(feat, Wself1, Wneigh1, S1, N1);

    aggregate1<<<(N_NODES + 7) / 8, 256, 0, stream>>>(N1, S1, b1, csr, beg, cur, h1);

    gemm2<<<(N_NODES + 63) / 64, 256, 0, stream>>>(h1, Wself2, Wneigh2, S2, N2);

    aggregate2<<<(N_NODES + 31) / 32, 256, 0, stream>>>(N2, S2, b2, csr, beg, cur, h2);

    pool_kernel<<<(N_NODES + 255) / 256, 256, 0, stream>>>(h2, gids, pool, cnt);

    head<<<1, 64, 0, stream>>>(pool, cnt, fc1w, fc1b, fc2w, fc2b, (float*)d_out);
}

// Round 12
// 288.548 us; speedup vs baseline: 1.3815x; 1.3815x over previous
//
#include <hip/hip_runtime.h>
#include <cstddef>

#define N_NODES  100000
#define N_EDGES  600000
#define N_GRAPHS 64

__device__ __forceinline__ void atomAddF(float* p, float v) {
    unsafeAtomicAdd(p, v);
}

__device__ __forceinline__ float f4get(const float4& v, int i) {
    return i == 0 ? v.x : i == 1 ? v.y : i == 2 ? v.z : v.w;
}

typedef __attribute__((address_space(1))) void GV;
typedef __attribute__((address_space(3))) void LV;
__device__ __forceinline__ void gload16(const float* g, float* l) {
    __builtin_amdgcn_global_load_lds((GV*)g, (LV*)l, 16, 0, 0);
}

// ---------------------------------------------------------------------------
__global__ __launch_bounds__(256) void deg_count(const int* __restrict__ dst,
                                                 int* __restrict__ deg) {
    int e = blockIdx.x * 256 + threadIdx.x;
    if (e < N_EDGES) atomicAdd(deg + dst[e], 1);
}

// ---------------------------------------------------------------------------
__global__ __launch_bounds__(256)
void alloc_ranges(const int* __restrict__ deg, int* __restrict__ beg,
                  int* __restrict__ cur, int* __restrict__ counter) {
    int n = blockIdx.x * 256 + threadIdx.x;
    int d = (n < N_NODES) ? deg[n] : 0;
    int lane = threadIdx.x & 63, wid = threadIdx.x >> 6;
    int incl = d;
#pragma unroll
    for (int o = 1; o < 64; o <<= 1) {
        int v = __shfl_up(incl, o);
        if (lane >= o) incl += v;
    }
    __shared__ int wsum[4];
    __shared__ int blockBase;
    if (lane == 63) wsum[wid] = incl;
    __syncthreads();
    if (threadIdx.x == 0) {
        int tot = wsum[0] + wsum[1] + wsum[2] + wsum[3];
        blockBase = atomicAdd(counter, tot);
    }
    __syncthreads();
    int base = blockBase;
    for (int w = 0; w < wid; ++w) base += wsum[w];
    int start = base + incl - d;
    if (n < N_NODES) { beg[n] = start; cur[n] = start; }
}

// ---------------------------------------------------------------------------
__global__ __launch_bounds__(256)
void csr_fill(const int* __restrict__ src, const int* __restrict__ dst,
              int* __restrict__ cur, int* __restrict__ csr_src) {
    int e = blockIdx.x * 256 + threadIdx.x;
    if (e >= N_EDGES) return;
    int p = atomicAdd(cur + dst[e], 1);
    csr_src[p] = src[e];
}

// ---------------------------------------------------------------------------
// GEMM1 (round-8 structure, measured 87us): BM=40, BN=200, KB=16, single-buf.
// A via global_load_lds with source pre-swizzle; vectorized A reads.
__global__ __launch_bounds__(256, 6)
void gemm1(const float* __restrict__ feat, const float* __restrict__ Wself,
           const float* __restrict__ Wneigh,
           float* __restrict__ S1, float* __restrict__ N1) {
    __shared__ float As[40 * 16];
    __shared__ float Bs[16][200];
    const int tid  = threadIdx.x;
    const int m0   = blockIdx.x * 40;
    const int wave = tid >> 6;
    const int lane = tid & 63;
    const bool active = tid < 250;
    const int tr  = tid / 25;
    const int tcc = tid % 25;
    const int sw  = tr & 3;

    float4 acc0[4], acc1[4];
#pragma unroll
    for (int i = 0; i < 4; ++i) {
        acc0[i] = make_float4(0.f, 0.f, 0.f, 0.f);
        acc1[i] = make_float4(0.f, 0.f, 0.f, 0.f);
    }

    for (int kt = 0; kt < 8; ++kt) {
        const int k0 = kt * 16;
        if (kt) __syncthreads();

        if (lane < 40) {
            int u  = wave * 40 + lane;
            int r  = u >> 2;
            int k4 = (u & 3) ^ ((r >> 2) & 3);
            gload16(feat + (size_t)(m0 + r) * 128 + k0 + k4 * 4, &As[wave * 160]);
        }
        for (int idx = tid; idx < 800; idx += 256) {
            int k = idx / 50, n4 = idx % 50;
            int n = n4 * 4;
            int gk = k0 + k;
            float4 v;
            if (n < 100) v = *reinterpret_cast<const float4*>(Wself + gk * 100 + n);
            else         v = *reinterpret_cast<const float4*>(Wneigh + gk * 100 + (n - 100));
            *reinterpret_cast<float4*>(&Bs[k][n]) = v;
        }
        __syncthreads();

        if (active) {
            const int abase = tr * 64;
#pragma unroll
            for (int g = 0; g < 4; ++g) {
                const int ac = ((g ^ sw) << 2);
                const float4 a0 = *reinterpret_cast<const float4*>(&As[abase +  0 + ac]);
                const float4 a1 = *reinterpret_cast<const float4*>(&As[abase + 16 + ac]);
                const float4 a2 = *reinterpret_cast<const float4*>(&As[abase + 32 + ac]);
                const float4 a3 = *reinterpret_cast<const float4*>(&As[abase + 48 + ac]);
#pragma unroll
                for (int kl = 0; kl < 4; ++kl) {
                    const int k = g * 4 + kl;
                    const float4 b0 = *reinterpret_cast<const float4*>(&Bs[k][tcc * 4]);
                    const float4 b1 = *reinterpret_cast<const float4*>(&Bs[k][100 + tcc * 4]);
                    const float v0 = f4get(a0, kl), v1 = f4get(a1, kl);
                    const float v2 = f4get(a2, kl), v3 = f4get(a3, kl);
                    acc0[0].x = fmaf(v0, b0.x, acc0[0].x); acc0[0].y = fmaf(v0, b0.y, acc0[0].y);
                    acc0[0].z = fmaf(v0, b0.z, acc0[0].z); acc0[0].w = fmaf(v0, b0.w, acc0[0].w);
                    acc1[0].x = fmaf(v0, b1.x, acc1[0].x); acc1[0].y = fmaf(v0, b1.y, acc1[0].y);
                    acc1[0].z = fmaf(v0, b1.z, acc1[0].z); acc1[0].w = fmaf(v0, b1.w, acc1[0].w);
                    acc0[1].x = fmaf(v1, b0.x, acc0[1].x); acc0[1].y = fmaf(v1, b0.y, acc0[1].y);
                    acc0[1].z = fmaf(v1, b0.z, acc0[1].z); acc0[1].w = fmaf(v1, b0.w, acc0[1].w);
                    acc1[1].x = fmaf(v1, b1.x, acc1[1].x); acc1[1].y = fmaf(v1, b1.y, acc1[1].y);
                    acc1[1].z = fmaf(v1, b1.z, acc1[1].z); acc1[1].w = fmaf(v1, b1.w, acc1[1].w);
                    acc0[2].x = fmaf(v2, b0.x, acc0[2].x); acc0[2].y = fmaf(v2, b0.y, acc0[2].y);
                    acc0[2].z = fmaf(v2, b0.z, acc0[2].z); acc0[2].w = fmaf(v2, b0.w, acc0[2].w);
                    acc1[2].x = fmaf(v2, b1.x, acc1[2].x); acc1[2].y = fmaf(v2, b1.y, acc1[2].y);
                    acc1[2].z = fmaf(v2, b1.z, acc1[2].z); acc1[2].w = fmaf(v2, b1.w, acc1[2].w);
                    acc0[3].x = fmaf(v3, b0.x, acc0[3].x); acc0[3].y = fmaf(v3, b0.y, acc0[3].y);
                    acc0[3].z = fmaf(v3, b0.z, acc0[3].z); acc0[3].w = fmaf(v3, b0.w, acc0[3].w);
                    acc1[3].x = fmaf(v3, b1.x, acc1[3].x); acc1[3].y = fmaf(v3, b1.y, acc1[3].y);
                    acc1[3].z = fmaf(v3, b1.z, acc1[3].z); acc1[3].w = fmaf(v3, b1.w, acc1[3].w);
                }
            }
        }
    }

    if (active) {
        const int c = tcc * 4;
#pragma unroll
        for (int i = 0; i < 4; ++i) {
            int gr = m0 + tr * 4 + i;
            *reinterpret_cast<float4*>(S1 + (size_t)gr * 100 + c) = acc0[i];
            *reinterpret_cast<float4*>(N1 + (size_t)gr * 100 + c) = acc1[i];
        }
    }
}

// ---------------------------------------------------------------------------
// agg1_gemm2: FUSED aggregate1 + gemm2.  Per block: 8 nodes.
// Phase 1: gather h1[n] = relu(S1[n] + (sum N1[src])*inv + b1) into LDS
//          (8 nodes x 32 lanes, 25 live float4 cols, 4x-unrolled gather).
// Phase 2: [S2|N2][8 x 40] = Hs[8 x 100] @ W2lds[100 x 40] (k-ascending
//          scalar dots == old gemm2 accumulation order).
// Saves the 40MB h1 write + 40MB h1 re-read + one launch.
// LDS: Hs 8x104 (3.3KB) + Bs2 100x40 (16KB) = 19.3KB.
__global__ __launch_bounds__(256)
void agg1_gemm2(const float* __restrict__ N1, const float* __restrict__ S1,
                const float* __restrict__ b1, const int* __restrict__ csr_src,
                const int* __restrict__ beg, const int* __restrict__ cur,
                const float* __restrict__ Ws2, const float* __restrict__ Wn2,
                float* __restrict__ S2, float* __restrict__ N2) {
    __shared__ float Hs[8][104];    // pad 104: phase-2 row stride spreads banks
    __shared__ float Bs2[100][40];
    const int tid  = threadIdx.x;
    const int nloc = tid >> 5;      // 0..7
    const int c4   = tid & 31;      // 0..31 (live < 25)
    const int n    = blockIdx.x * 8 + nloc;   // grid exact: 12500*8 = 100000

    // W2 -> LDS: 1000 float4
    for (int idx = tid; idx < 1000; idx += 256) {
        int k = idx / 10;
        int col = (idx % 10) * 4;
        float4 v;
        if (col < 20) v = *reinterpret_cast<const float4*>(Ws2 + k * 20 + col);
        else          v = *reinterpret_cast<const float4*>(Wn2 + k * 20 + (col - 20));
        *reinterpret_cast<float4*>(&Bs2[k][col]) = v;
    }

    if (c4 < 25) {
        int b = beg[n], end = cur[n];
        float4 acc = make_float4(0.f, 0.f, 0.f, 0.f);
        int j = b;
        for (; j + 3 < end; j += 4) {
            int s0 = csr_src[j], s1 = csr_src[j + 1], s2 = csr_src[j + 2], s3 = csr_src[j + 3];
            float4 v0 = *reinterpret_cast<const float4*>(N1 + (size_t)s0 * 100 + c4 * 4);
            float4 v1 = *reinterpret_cast<const float4*>(N1 + (size_t)s1 * 100 + c4 * 4);
            float4 v2 = *reinterpret_cast<const float4*>(N1 + (size_t)s2 * 100 + c4 * 4);
            float4 v3 = *reinterpret_cast<const float4*>(N1 + (size_t)s3 * 100 + c4 * 4);
            acc.x += v0.x + v1.x; acc.y += v0.y + v1.y;
            acc.z += v0.z + v1.z; acc.w += v0.w + v1.w;
            acc.x += v2.x + v3.x; acc.y += v2.y + v3.y;
            acc.z += v2.z + v3.z; acc.w += v2.w + v3.w;
        }
        for (; j + 1 < end; j += 2) {
            int s0 = csr_src[j], s1 = csr_src[j + 1];
            float4 v0 = *reinterpret_cast<const float4*>(N1 + (size_t)s0 * 100 + c4 * 4);
            float4 v1 = *reinterpret_cast<const float4*>(N1 + (size_t)s1 * 100 + c4 * 4);
            acc.x += v0.x + v1.x; acc.y += v0.y + v1.y;
            acc.z += v0.z + v1.z; acc.w += v0.w + v1.w;
        }
        if (j < end) {
            int s = csr_src[j];
            float4 v = *reinterpret_cast<const float4*>(N1 + (size_t)s * 100 + c4 * 4);
            acc.x += v.x; acc.y += v.y; acc.z += v.z; acc.w += v.w;
        }
        float inv = 1.0f / (float)max(end - b, 1);
        float4 s  = *reinterpret_cast<const float4*>(S1 + (size_t)n * 100 + c4 * 4);
        float4 bb = *reinterpret_cast<const float4*>(b1 + c4 * 4);
        float4 h;
        h.x = fmaxf(fmaf(acc.x, inv, s.x) + bb.x, 0.f);
        h.y = fmaxf(fmaf(acc.y, inv, s.y) + bb.y, 0.f);
        h.z = fmaxf(fmaf(acc.z, inv, s.z) + bb.z, 0.f);
        h.w = fmaxf(fmaf(acc.w, inv, s.w) + bb.w, 0.f);
        *reinterpret_cast<float4*>(&Hs[nloc][c4 * 4]) = h;
    }
    __syncthreads();

    // Phase 2: 320 outputs (8 nodes x 40 cols), 2 strided passes
    for (int idx = tid; idx < 320; idx += 256) {
        int nl = idx / 40, col = idx % 40;
        float a = 0.f;
#pragma unroll 4
        for (int k = 0; k < 100; ++k)
            a = fmaf(Hs[nl][k], Bs2[k][col], a);
        int gn = blockIdx.x * 8 + nl;
        if (col < 20) S2[(size_t)gn * 20 + col] = a;
        else          N2[(size_t)gn * 20 + (col - 20)] = a;
    }
}

// ---------------------------------------------------------------------------
// aggregate2 + fused h2 epilogue: h2 = relu(S2 + (sum N2[src])*inv + b2).
__global__ __launch_bounds__(256)
void aggregate2(const float* __restrict__ N2, const float* __restrict__ S2,
                const float* __restrict__ b2, const int* __restrict__ csr_src,
                const int* __restrict__ beg, const int* __restrict__ cur,
                float* __restrict__ h2) {
    int n  = blockIdx.x * 32 + (threadIdx.x >> 3);
    int c4 = threadIdx.x & 7;
    if (n >= N_NODES || c4 >= 5) return;
    int b = beg[n], end = cur[n];
    float4 acc = make_float4(0.f, 0.f, 0.f, 0.f);
    int j = b;
    for (; j + 3 < end; j += 4) {
        int s0 = csr_src[j], s1 = csr_src[j + 1], s2 = csr_src[j + 2], s3 = csr_src[j + 3];
        float4 v0 = *reinterpret_cast<const float4*>(N2 + (size_t)s0 * 20 + c4 * 4);
        float4 v1 = *reinterpret_cast<const float4*>(N2 + (size_t)s1 * 20 + c4 * 4);
        float4 v2 = *reinterpret_cast<const float4*>(N2 + (size_t)s2 * 20 + c4 * 4);
        float4 v3 = *reinterpret_cast<const float4*>(N2 + (size_t)s3 * 20 + c4 * 4);
        acc.x += v0.x + v1.x; acc.y += v0.y + v1.y;
        acc.z += v0.z + v1.z; acc.w += v0.w + v1.w;
        acc.x += v2.x + v3.x; acc.y += v2.y + v3.y;
        acc.z += v2.z + v3.z; acc.w += v2.w + v3.w;
    }
    for (; j + 1 < end; j += 2) {
        int s0 = csr_src[j], s1 = csr_src[j + 1];
        float4 v0 = *reinterpret_cast<const float4*>(N2 + (size_t)s0 * 20 + c4 * 4);
        float4 v1 = *reinterpret_cast<const float4*>(N2 + (size_t)s1 * 20 + c4 * 4);
        acc.x += v0.x + v1.x; acc.y += v0.y + v1.y;
        acc.z += v0.z + v1.z; acc.w += v0.w + v1.w;
    }
    if (j < end) {
        int s = csr_src[j];
        float4 v = *reinterpret_cast<const float4*>(N2 + (size_t)s * 20 + c4 * 4);
        acc.x += v.x; acc.y += v.y; acc.z += v.z; acc.w += v.w;
    }
    float inv = 1.0f / (float)max(end - b, 1);
    float4 s  = *reinterpret_cast<const float4*>(S2 + (size_t)n * 20 + c4 * 4);
    float4 bb = *reinterpret_cast<const float4*>(b2 + c4 * 4);
    float4 h;
    h.x = fmaxf(fmaf(acc.x, inv, s.x) + bb.x, 0.f);
    h.y = fmaxf(fmaf(acc.y, inv, s.y) + bb.y, 0.f);
    h.z = fmaxf(fmaf(acc.z, inv, s.z) + bb.z, 0.f);
    h.w = fmaxf(fmaf(acc.w, inv, s.w) + bb.w, 0.f);
    *reinterpret_cast<float4*>(h2 + (size_t)n * 20 + c4 * 4) = h;
}

// ---------------------------------------------------------------------------
__global__ __launch_bounds__(256)
void pool_kernel(const float* __restrict__ h2, const int* __restrict__ gids,
                 float* __restrict__ pool, float* __restrict__ cnt) {
    int n = blockIdx.x * 256 + threadIdx.x;
    float h[20];
    int g = -1;
    if (n < N_NODES) {
        g = gids[n];
#pragma unroll
        for (int q = 0; q < 5; ++q) {
            float4 v = *reinterpret_cast<const float4*>(h2 + (size_t)n * 20 + q * 4);
            h[q * 4 + 0] = v.x; h[q * 4 + 1] = v.y;
            h[q * 4 + 2] = v.z; h[q * 4 + 3] = v.w;
        }
    } else {
#pragma unroll
        for (int c = 0; c < 20; ++c) h[c] = 0.f;
    }
    unsigned long long act = __ballot(n < N_NODES);
    int gfirst = __shfl(g, 0);
    bool uniform = __all(g == gfirst);
    if (uniform) {
        if (gfirst >= 0) {
#pragma unroll
            for (int c = 0; c < 20; ++c)
                for (int off2 = 32; off2 > 0; off2 >>= 1)
                    h[c] += __shfl_down(h[c], off2);
            if ((threadIdx.x & 63) == 0) {
                for (int c = 0; c < 20; ++c) atomAddF(&pool[gfirst * 20 + c], h[c]);
                atomAddF(&cnt[gfirst], (float)__popcll(act));
            }
        }
    } else if (n < N_NODES) {
        for (int c = 0; c < 20; ++c) atomAddF(&pool[g * 20 + c], h[c]);
        atomAddF(&cnt[g], 1.0f);
    }
}

// ---------------------------------------------------------------------------
__global__ __launch_bounds__(64)
void head(const float* __restrict__ pool, const float* __restrict__ cnt,
          const float* __restrict__ fc1w, const float* __restrict__ fc1b,
          const float* __restrict__ fc2w, const float* __restrict__ fc2b,
          float* __restrict__ out) {
    int g = threadIdx.x;
    if (g >= N_GRAPHS) return;
    float inv = 1.0f / fmaxf(cnt[g], 1.0f);
    float hg[20];
    for (int c = 0; c < 20; ++c) hg[c] = pool[g * 20 + c] * inv;
    float o = fc2b[0];
    for (int j = 0; j < 10; ++j) {
        float t = fc1b[j];
        for (int c = 0; c < 20; ++c) t = fmaf(hg[c], fc1w[c * 10 + j], t);
        o = fmaf(fmaxf(t, 0.f), fc2w[j], o);
    }
    out[g] = o;
}

// ---------------------------------------------------------------------------
extern "C" void kernel_launch(void* const* d_in, const int* in_sizes, int n_in,
                              void* d_out, int out_size, void* d_ws, size_t ws_size,
                              hipStream_t stream) {
    const float* feat   = (const float*)d_in[0];
    const float* Wself1 = (const float*)d_in[1];
    const float* Wneigh1= (const float*)d_in[2];
    const float* b1     = (const float*)d_in[3];
    const float* Wself2 = (const float*)d_in[4];
    const float* Wneigh2= (const float*)d_in[5];
    const float* b2     = (const float*)d_in[6];
    const float* fc1w   = (const float*)d_in[7];
    const float* fc1b   = (const float*)d_in[8];
    const float* fc2w   = (const float*)d_in[9];
    const float* fc2b   = (const float*)d_in[10];
    const int*   src    = (const int*)d_in[11];
    const int*   dst    = (const int*)d_in[12];
    const int*   gids   = (const int*)d_in[13];
    float* ws = (float*)d_ws;

    // workspace layout (floats)
    float* S1 = ws;                        // 10,000,000 (dead after agg1_gemm2)
    float* N1 = ws + 10000000;             // 10,000,000 (dead after agg1_gemm2)
    float* S2 = ws + 20000000;             //  2,000,000 (own region: written while N1/S1 read)
    float* N2 = ws + 22000000;             //  2,000,000
    float* h2 = ws;                        //  2,000,000 (S1 region, dead by then)
    int*   deg  = (int*)(ws + 30000000);   //    100,000
    float* pool = ws + 30100000;           //      1,280
    float* cnt  = ws + 30101280;           //         64
    int*   ctr  = (int*)(ws + 30101344);   //          1
    int*   beg  = (int*)(ws + 30101360);   //    100,000
    int*   cur  = (int*)(ws + 30201360);   //    100,000
    int*   csr  = (int*)(ws + 30301360);   //    600,000
    // total: 30,901,360 floats = ~117.9 MiB

    hipMemsetAsync(deg, 0, (100000 + 1280 + 64 + 16) * sizeof(float), stream);

    deg_count<<<(N_EDGES + 255) / 256, 256, 0, stream>>>(dst, deg);
    alloc_ranges<<<(N_NODES + 255) / 256, 256, 0, stream>>>(deg, beg, cur, ctr);
    csr_fill<<<(N_EDGES + 255) / 256, 256, 0, stream>>>(src, dst, cur, csr);

    gemm1<<<N_NODES / 40, 256, 0, stream>>>(feat, Wself1, Wneigh1, S1, N1);

    agg1_gemm2<<<N_NODES / 8, 256, 0, stream>>>(N1, S1, b1, csr, beg, cur,
                                                Wself2, Wneigh2, S2, N2);

    aggregate2<<<(N_NODES + 31) / 32, 256, 0, stream>>>(N2, S2, b2, csr, beg, cur, h2);

    pool_kernel<<<(N_NODES + 255) / 256, 256, 0, stream>>>(h2, gids, pool, cnt);

    head<<<1, 64, 0, stream>>>(pool, cnt, fc1w, fc1b, fc2w, fc2b, (float*)d_out);
}